// Round 1
// baseline (577.746 us; speedup 1.0000x reference)
//
#include <hip/hip_runtime.h>
#include <stdint.h>

// B=1024, T=187, H=256, C=5. Fully-fused persistent 2-layer RNN + FC.
// 64 blocks x 16 batch rows, 4 waves/block, each wave owns a 64-wide N-slice
// of all three weight matrices in registers (bf16 fragments). h0/h1 states
// round-trip through LDS each step (MFMA A-operand layout).

#define Bsz 1024
#define Tt  187
#define Hh  256
#define Cc  5
#define HS  264   // LDS row stride in bf16 elements (256 + 8 pad -> conflict-free b128 reads)

typedef short bf16x8 __attribute__((ext_vector_type(8)));
typedef float f32x4  __attribute__((ext_vector_type(4)));

__device__ __forceinline__ unsigned short f2bf(float f) {
    union { float f; unsigned u; } v; v.f = f;
    return (unsigned short)((v.u + 0x7fffu + ((v.u >> 16) & 1u)) >> 16);  // RNE
}
__device__ __forceinline__ float bf2f(unsigned short b) {
    union { unsigned u; float f; } v; v.u = ((unsigned)b) << 16;
    return v.f;
}
// tanh(z) = 1 - 2/(1+e^{2z});  inf-safe at both tails, 2 transcendental ops.
__device__ __forceinline__ float tanh_fast(float z) {
    float e = __expf(2.0f * z);
    return 1.0f - 2.0f * __builtin_amdgcn_rcpf(1.0f + e);
}

__global__ __launch_bounds__(256, 1)
void rnn_fused(const float* __restrict__ x,     // [B][T]
               const float* __restrict__ Wih0,  // [H][1]
               const float* __restrict__ Whh0,  // [H][H]
               const float* __restrict__ bih0,
               const float* __restrict__ bhh0,
               const float* __restrict__ Wih1,  // [H][H]
               const float* __restrict__ Whh1,  // [H][H]
               const float* __restrict__ bih1,
               const float* __restrict__ bhh1,
               const float* __restrict__ Wfc,   // [C][H]
               const float* __restrict__ bfc,   // [C]
               float* __restrict__ out)         // [B][C]
{
    __shared__ __align__(16) unsigned short h0s[16 * HS];
    __shared__ __align__(16) unsigned short h1s[16 * HS];

    const int tid  = threadIdx.x;
    const int lane = tid & 63;
    const int wv   = tid >> 6;     // wave 0..3 -> N-slice [64*wv, 64*wv+64)
    const int q    = lane >> 4;    // quad 0..3
    const int c    = lane & 15;
    const int nb   = wv * 64;
    const int bb   = blockIdx.x * 16;

    // ---- one-time: stage weight fragments into registers (bf16) ----
    // B-operand layout for mfma_f32_16x16x32_bf16: B[k][n], n = lane&15,
    // k = (lane>>4)*8 + j  => lane holds W[n][kt*32 + q*8 .. +8] (8 contiguous).
    bf16x8 wh0[4][8], wi1[4][8], wh1[4][8];
    float wih0c[4], b0c[4], b1c[4];
#pragma unroll
    for (int nt = 0; nt < 4; ++nt) {
        const int n = nb + nt * 16 + c;
        wih0c[nt] = Wih0[n];
        b0c[nt]   = bih0[n] + bhh0[n];
        b1c[nt]   = bih1[n] + bhh1[n];
#pragma unroll
        for (int kt = 0; kt < 8; ++kt) {
            const int off = n * Hh + kt * 32 + q * 8;
            {
                const float4 a0 = *(const float4*)(Whh0 + off);
                const float4 a1 = *(const float4*)(Whh0 + off + 4);
                bf16x8 f;
                f[0]=(short)f2bf(a0.x); f[1]=(short)f2bf(a0.y); f[2]=(short)f2bf(a0.z); f[3]=(short)f2bf(a0.w);
                f[4]=(short)f2bf(a1.x); f[5]=(short)f2bf(a1.y); f[6]=(short)f2bf(a1.z); f[7]=(short)f2bf(a1.w);
                wh0[nt][kt] = f;
            }
            {
                const float4 a0 = *(const float4*)(Wih1 + off);
                const float4 a1 = *(const float4*)(Wih1 + off + 4);
                bf16x8 f;
                f[0]=(short)f2bf(a0.x); f[1]=(short)f2bf(a0.y); f[2]=(short)f2bf(a0.z); f[3]=(short)f2bf(a0.w);
                f[4]=(short)f2bf(a1.x); f[5]=(short)f2bf(a1.y); f[6]=(short)f2bf(a1.z); f[7]=(short)f2bf(a1.w);
                wi1[nt][kt] = f;
            }
            {
                const float4 a0 = *(const float4*)(Whh1 + off);
                const float4 a1 = *(const float4*)(Whh1 + off + 4);
                bf16x8 f;
                f[0]=(short)f2bf(a0.x); f[1]=(short)f2bf(a0.y); f[2]=(short)f2bf(a0.z); f[3]=(short)f2bf(a0.w);
                f[4]=(short)f2bf(a1.x); f[5]=(short)f2bf(a1.y); f[6]=(short)f2bf(a1.z); f[7]=(short)f2bf(a1.w);
                wh1[nt][kt] = f;
            }
        }
    }

    // ---- init states: h1 = 0; h0 = hs0[t=0] = tanh(x[:,0]*wih0 + b0) ----
    for (int i = tid; i < 16 * HS; i += 256) h1s[i] = 0;
#pragma unroll
    for (int nt = 0; nt < 4; ++nt)
#pragma unroll
        for (int r = 0; r < 4; ++r) {
            float xv = x[(bb + 4 * q + r) * Tt];
            h0s[(4 * q + r) * HS + nb + nt * 16 + c] =
                f2bf(tanh_fast(xv * wih0c[nt] + b0c[nt]));
        }
    __syncthreads();

    // A-operand read base: A[m=lane&15][k=q*8+j] -> row c, byte-contiguous 16B
    const unsigned short* a0p = &h0s[c * HS + q * 8];
    const unsigned short* a1p = &h1s[c * HS + q * 8];
    const int wrow = 4 * q;
    int xbase[4];
#pragma unroll
    for (int r = 0; r < 4; ++r) xbase[r] = (bb + 4 * q + r) * Tt;

    // ---- main recurrence, time-skewed:
    // iter s: A0 = hs0[s]; produces hs0[s+1] (via Whh0) and hs1[s] (via Wih1+Whh1)
#pragma unroll 1
    for (int s = 0; s < Tt; ++s) {
        const int sn = (s + 1 < Tt) ? s + 1 : Tt - 1;  // clamped (last iter's h0_next unused)
        float xv[4];
#pragma unroll
        for (int r = 0; r < 4; ++r) xv[r] = x[xbase[r] + sn];

        f32x4 ai[4], ah0[4];
#pragma unroll
        for (int nt = 0; nt < 4; ++nt) {
            ai[nt]  = (f32x4){b1c[nt], b1c[nt], b1c[nt], b1c[nt]};
            ah0[nt] = (f32x4){b0c[nt], b0c[nt], b0c[nt], b0c[nt]};
        }
        // A0 read once, feeds BOTH Wih1 (xp1_s) and Whh0 (h0_{s+1})
#pragma unroll
        for (int kt = 0; kt < 8; ++kt) {
            bf16x8 A = *(const bf16x8*)(a0p + kt * 32);
#pragma unroll
            for (int nt = 0; nt < 4; ++nt) {
                ai[nt]  = __builtin_amdgcn_mfma_f32_16x16x32_bf16(A, wi1[nt][kt], ai[nt],  0, 0, 0);
                ah0[nt] = __builtin_amdgcn_mfma_f32_16x16x32_bf16(A, wh0[nt][kt], ah0[nt], 0, 0, 0);
            }
        }
        // h0_next = tanh(acc + x_{s+1}*wih0 + b0)   (overlaps with hh1 MFMAs below)
#pragma unroll
        for (int nt = 0; nt < 4; ++nt)
#pragma unroll
            for (int r = 0; r < 4; ++r)
                ah0[nt][r] = tanh_fast(ah0[nt][r] + xv[r] * wih0c[nt]);

        f32x4 ah1[4];
#pragma unroll
        for (int nt = 0; nt < 4; ++nt) ah1[nt] = (f32x4){0.f, 0.f, 0.f, 0.f};
#pragma unroll
        for (int kt = 0; kt < 8; ++kt) {
            bf16x8 A = *(const bf16x8*)(a1p + kt * 32);
#pragma unroll
            for (int nt = 0; nt < 4; ++nt)
                ah1[nt] = __builtin_amdgcn_mfma_f32_16x16x32_bf16(A, wh1[nt][kt], ah1[nt], 0, 0, 0);
        }
        // h1_s = tanh(xp1_s + b1 + h1_{s-1} @ Whh1^T)
#pragma unroll
        for (int nt = 0; nt < 4; ++nt)
#pragma unroll
            for (int r = 0; r < 4; ++r)
                ai[nt][r] = tanh_fast(ai[nt][r] + ah1[nt][r]);

        __syncthreads();   // all waves' LDS reads of step s complete
        // D layout: row m = 4*q + r, col n = nb + nt*16 + c
#pragma unroll
        for (int nt = 0; nt < 4; ++nt)
#pragma unroll
            for (int r = 0; r < 4; ++r) {
                h0s[(wrow + r) * HS + nb + nt * 16 + c] = f2bf(ah0[nt][r]);
                h1s[(wrow + r) * HS + nb + nt * 16 + c] = f2bf(ai[nt][r]);
            }
        __syncthreads();   // writes visible before next step's reads
    }

    // ---- FC epilogue: out[bb+m][cls] = h1_final . Wfc[cls] + bfc[cls] ----
    if (tid < 16 * Cc) {
        const int m = tid / Cc, cls = tid - Cc * (tid / Cc);
        float acc = bfc[cls];
        for (int k = 0; k < Hh; ++k)
            acc += bf2f(h1s[m * HS + k]) * Wfc[cls * Hh + k];
        out[(bb + m) * Cc + cls] = acc;
    }
}

extern "C" void kernel_launch(void* const* d_in, const int* in_sizes, int n_in,
                              void* d_out, int out_size, void* d_ws, size_t ws_size,
                              hipStream_t stream) {
    rnn_fused<<<dim3(Bsz / 16), dim3(256), 0, stream>>>(
        (const float*)d_in[0],  // x
        (const float*)d_in[1],  // W_ih0
        (const float*)d_in[2],  // W_hh0
        (const float*)d_in[3],  // b_ih0
        (const float*)d_in[4],  // b_hh0
        (const float*)d_in[5],  // W_ih1
        (const float*)d_in[6],  // W_hh1
        (const float*)d_in[7],  // b_ih1
        (const float*)d_in[8],  // b_hh1
        (const float*)d_in[9],  // W_fc
        (const float*)d_in[10], // b_fc
        (float*)d_out);
}

// Round 3
// 373.545 us; speedup vs baseline: 1.5467x; 1.5467x over previous
//
#include <hip/hip_runtime.h>
#include <stdint.h>

// B=1024, T=187, H=256, C=5. Fully-fused persistent 2-layer RNN + FC.
// Transposed recurrence: ht = h^T stored in LDS as [batch col][feature],
// so state is the MFMA B-operand and weights (A-operand, f16 fragments)
// stay register-resident. 64 blocks x 16 batch cols, 8 waves/block, each
// wave owns a 32-feature M-slice of all three weight matrices (192 VGPRs).
// Double-buffered state -> 1 barrier/step.

#define Bsz 1024
#define Tt  187
#define Hh  256
#define Cc  5
#define ST  264      // f16 elems per batch-col row (256 + 8 pad, bank-friendly)
#define XS  188      // x LDS stride (187 + 1)

typedef _Float16 f16x8 __attribute__((ext_vector_type(8)));
typedef __fp16   fp16x2 __attribute__((ext_vector_type(2)));  // cvt_pkrtz native type
typedef float    f32x4 __attribute__((ext_vector_type(4)));

__device__ __forceinline__ float tanh_fast(float z) {
    float e = __expf(2.0f * z);
    return 1.0f - 2.0f * __builtin_amdgcn_rcpf(1.0f + e);
}

__device__ __forceinline__ unsigned pk2(float a, float b) {
    union { fp16x2 h; unsigned u; } v;
    v.h = __builtin_amdgcn_cvt_pkrtz(a, b);
    return v.u;
}

__global__ __launch_bounds__(512, 2)
void rnn_fused(const float* __restrict__ x,     // [B][T]
               const float* __restrict__ Wih0,  // [H][1]
               const float* __restrict__ Whh0,  // [H][H]
               const float* __restrict__ bih0,
               const float* __restrict__ bhh0,
               const float* __restrict__ Wih1,  // [H][H]
               const float* __restrict__ Whh1,  // [H][H]
               const float* __restrict__ bih1,
               const float* __restrict__ bhh1,
               const float* __restrict__ Wfc,   // [C][H]
               const float* __restrict__ bfc,   // [C]
               float* __restrict__ out)         // [B][C]
{
    __shared__ __align__(16) _Float16 ht0[2][16 * ST];
    __shared__ __align__(16) _Float16 ht1[2][16 * ST];
    __shared__ float xs[16 * XS];

    const int tid  = threadIdx.x;
    const int lane = tid & 63;
    const int w    = tid >> 6;     // wave 0..7 -> features [32w, 32w+32)
    const int q    = lane >> 4;
    const int c    = lane & 15;    // batch col within block
    const int bb   = blockIdx.x * 16;

    // ---- one-time: stage weight A-fragments into registers (f16) ----
    // A-layout: lane (q,c) reg j holds A[m=c][k=kt*32+q*8+j],
    // 8 contiguous elements of row (fb+c).
    f16x8 wh0[2][8], wi1[2][8], wh1[2][8];
    f32x4 b0v[2], b1v[2], wi0v[2];   // per (mt,r): feature fb+4q+r (C/D layout)
#pragma unroll
    for (int mt = 0; mt < 2; ++mt) {
        const int fb = 32 * w + 16 * mt;
#pragma unroll
        for (int r = 0; r < 4; ++r) {
            const int f = fb + 4 * q + r;
            b0v[mt][r]  = bih0[f] + bhh0[f];
            b1v[mt][r]  = bih1[f] + bhh1[f];
            wi0v[mt][r] = Wih0[f];
        }
        const int m = fb + c;
#pragma unroll
        for (int kt = 0; kt < 8; ++kt) {
            const int off = m * Hh + kt * 32 + q * 8;
            {
                const float4 a0 = *(const float4*)(Whh0 + off);
                const float4 a1 = *(const float4*)(Whh0 + off + 4);
                wh0[mt][kt] = (f16x8){(_Float16)a0.x, (_Float16)a0.y, (_Float16)a0.z, (_Float16)a0.w,
                                      (_Float16)a1.x, (_Float16)a1.y, (_Float16)a1.z, (_Float16)a1.w};
            }
            {
                const float4 a0 = *(const float4*)(Wih1 + off);
                const float4 a1 = *(const float4*)(Wih1 + off + 4);
                wi1[mt][kt] = (f16x8){(_Float16)a0.x, (_Float16)a0.y, (_Float16)a0.z, (_Float16)a0.w,
                                      (_Float16)a1.x, (_Float16)a1.y, (_Float16)a1.z, (_Float16)a1.w};
            }
            {
                const float4 a0 = *(const float4*)(Whh1 + off);
                const float4 a1 = *(const float4*)(Whh1 + off + 4);
                wh1[mt][kt] = (f16x8){(_Float16)a0.x, (_Float16)a0.y, (_Float16)a0.z, (_Float16)a0.w,
                                      (_Float16)a1.x, (_Float16)a1.y, (_Float16)a1.z, (_Float16)a1.w};
            }
        }
    }

    // ---- init LDS: x tile, ht1 = 0 (both buffers), ht0[0] = state t=0 ----
    for (int i = tid; i < 16 * Tt; i += 512) {
        const int b = i / Tt, t = i - b * Tt;
        xs[b * XS + t] = x[(bb + b) * Tt + t];
    }
    {
        _Float16* z = &ht1[0][0];
        for (int i = tid; i < 2 * 16 * ST; i += 512) z[i] = (_Float16)0.f;
    }
    for (int i = tid; i < 16 * Hh; i += 512) {
        const int b = i >> 8, f = i & 255;
        const float xv0 = x[(bb + b) * Tt];
        ht0[0][b * ST + f] =
            (_Float16)tanh_fast(xv0 * Wih0[f] + bih0[f] + bhh0[f]);
    }
    __syncthreads();

    // B-operand read base: lane (q,c) reg j needs ht[k=kt*32+q*8+j][col c]
    // -> LDS [c][kt*32+q*8], contiguous 16B (ds_read_b128).
    const int rdoff = c * ST + q * 8;
    const int wroff = c * ST + 32 * w + 4 * q;   // D write: [c][fb+4q .. +3]

    // ---- main recurrence, time-skewed:
    // step s: B0 = ht0[s]; produce ht0[s+1] (Whh0) and ht1[s] (Wih1 + Whh1)
#pragma unroll 1
    for (int s = 0; s < Tt; ++s) {
        const int cur = s & 1, nxt = cur ^ 1;
        const _Float16* B0p = &ht0[cur][rdoff];
        const _Float16* B1p = &ht1[nxt][rdoff];   // ht1[s-1]
        int sn = s + 1; if (sn >= Tt) sn = Tt - 1;  // last h0_next unused
        const float xv = xs[c * XS + sn];

        // layer0: ai = Wih1 . ht0 + b1 ; ah0 = Whh0 . ht0 + b0 (shared B-frag)
        f32x4 ai[2], ah0[2];
        {
            const f16x8 B = *(const f16x8*)B0p;
            ai[0]  = __builtin_amdgcn_mfma_f32_16x16x32_f16(wi1[0][0], B, b1v[0], 0, 0, 0);
            ai[1]  = __builtin_amdgcn_mfma_f32_16x16x32_f16(wi1[1][0], B, b1v[1], 0, 0, 0);
            ah0[0] = __builtin_amdgcn_mfma_f32_16x16x32_f16(wh0[0][0], B, b0v[0], 0, 0, 0);
            ah0[1] = __builtin_amdgcn_mfma_f32_16x16x32_f16(wh0[1][0], B, b0v[1], 0, 0, 0);
        }
#pragma unroll
        for (int kt = 1; kt < 8; ++kt) {
            const f16x8 B = *(const f16x8*)(B0p + kt * 32);
            ai[0]  = __builtin_amdgcn_mfma_f32_16x16x32_f16(wi1[0][kt], B, ai[0],  0, 0, 0);
            ai[1]  = __builtin_amdgcn_mfma_f32_16x16x32_f16(wi1[1][kt], B, ai[1],  0, 0, 0);
            ah0[0] = __builtin_amdgcn_mfma_f32_16x16x32_f16(wh0[0][kt], B, ah0[0], 0, 0, 0);
            ah0[1] = __builtin_amdgcn_mfma_f32_16x16x32_f16(wh0[1][kt], B, ah0[1], 0, 0, 0);
        }
        // ht0[s+1] = tanh(ah0 + x_{s+1} * wih0), pack f16, 8B LDS writes
#pragma unroll
        for (int mt = 0; mt < 2; ++mt) {
            const float t0 = tanh_fast(ah0[mt][0] + xv * wi0v[mt][0]);
            const float t1 = tanh_fast(ah0[mt][1] + xv * wi0v[mt][1]);
            const float t2 = tanh_fast(ah0[mt][2] + xv * wi0v[mt][2]);
            const float t3 = tanh_fast(ah0[mt][3] + xv * wi0v[mt][3]);
            *(uint2*)(&ht0[nxt][wroff + 16 * mt]) = make_uint2(pk2(t0, t1), pk2(t2, t3));
        }

        // layer1: ah1 = Whh1 . ht1[s-1]
        f32x4 ah1[2];
        {
            const f16x8 B = *(const f16x8*)B1p;
            const f32x4 z4 = (f32x4){0.f, 0.f, 0.f, 0.f};
            ah1[0] = __builtin_amdgcn_mfma_f32_16x16x32_f16(wh1[0][0], B, z4, 0, 0, 0);
            ah1[1] = __builtin_amdgcn_mfma_f32_16x16x32_f16(wh1[1][0], B, z4, 0, 0, 0);
        }
#pragma unroll
        for (int kt = 1; kt < 8; ++kt) {
            const f16x8 B = *(const f16x8*)(B1p + kt * 32);
            ah1[0] = __builtin_amdgcn_mfma_f32_16x16x32_f16(wh1[0][kt], B, ah1[0], 0, 0, 0);
            ah1[1] = __builtin_amdgcn_mfma_f32_16x16x32_f16(wh1[1][kt], B, ah1[1], 0, 0, 0);
        }
        // ht1[s] = tanh(ai + ah1)
#pragma unroll
        for (int mt = 0; mt < 2; ++mt) {
            const float t0 = tanh_fast(ai[mt][0] + ah1[mt][0]);
            const float t1 = tanh_fast(ai[mt][1] + ah1[mt][1]);
            const float t2 = tanh_fast(ai[mt][2] + ah1[mt][2]);
            const float t3 = tanh_fast(ai[mt][3] + ah1[mt][3]);
            *(uint2*)(&ht1[cur][wroff + 16 * mt]) = make_uint2(pk2(t0, t1), pk2(t2, t3));
        }
        __syncthreads();   // double-buffered: one barrier per step
    }

    // ---- FC epilogue: out[bb+b][cls] = ht1_final[.][b] . Wfc[cls] + bfc ----
    if (tid < 16 * Cc) {
        const int b = tid / Cc, cls = tid - Cc * (tid / Cc);
        const _Float16* h = &ht1[(Tt - 1) & 1][b * ST];
        float acc = bfc[cls];
        for (int k = 0; k < Hh; ++k)
            acc += (float)h[k] * Wfc[cls * Hh + k];
        out[(bb + b) * Cc + cls] = acc;
    }
}

extern "C" void kernel_launch(void* const* d_in, const int* in_sizes, int n_in,
                              void* d_out, int out_size, void* d_ws, size_t ws_size,
                              hipStream_t stream) {
    rnn_fused<<<dim3(Bsz / 16), dim3(512), 0, stream>>>(
        (const float*)d_in[0],  // x
        (const float*)d_in[1],  // W_ih0
        (const float*)d_in[2],  // W_hh0
        (const float*)d_in[3],  // b_ih0
        (const float*)d_in[4],  // b_hh0
        (const float*)d_in[5],  // W_ih1
        (const float*)d_in[6],  // W_hh1
        (const float*)d_in[7],  // b_ih1
        (const float*)d_in[8],  // b_hh1
        (const float*)d_in[9],  // W_fc
        (const float*)d_in[10], // b_fc
        (float*)d_out);
}